// Round 1
// baseline (59997.510 us; speedup 1.0000x reference)
//
#include <hip/hip_runtime.h>
#include <math.h>

// VarMaskedRNN: B=32, T=1024, IN=1024, H=512, L=2, D=2 (bidirectional), fp32.
// Structure:
//   proj (GEMM, time-parallel)  -> xin[c][T,B,H]   (ws)
//   rec  (1 WG per (dir,batch)) -> seq/out + finals
// Layer-0 hidden sequence seq0 [T,B,2H] is staged in d_out (overwritten by the
// final layer-1 output only after proj(layer1) has fully consumed it).

#define BB 32
#define TT 1024
#define HH 512
#define KK 1024   // input dim for both layers (IN == 2H == 1024)

// ---------------------------------------------------------------------------
// Input projection: dst[m, n] = sum_k src[row(m), k] * noise[b(m), k] * W[n, k]
//                              + bih[n]
// m = t*B + b (so dst is [T,B,H] directly). M=32768, K=1024, N=512.
// Tile 64(M) x 128(N), BK=16, 256 threads, 4x8 per thread (split-n halves for
// conflict-free LDS reads: 2-way bank aliasing only, which is free on gfx950).
// ---------------------------------------------------------------------------
__global__ __launch_bounds__(256)
void proj_kernel(const float* __restrict__ src, const float* __restrict__ noise,
                 const float* __restrict__ wih, const float* __restrict__ bih,
                 float* __restrict__ dst, int src_tmajor)
{
    __shared__ float As[16][68];    // [k][m], +4 pad keeps float4 rows 16B-aligned
    __shared__ float Bs[16][132];   // [k][n]

    const int tid = threadIdx.x;
    const int bm = blockIdx.x & 511;   // 512 M-blocks
    const int bn = blockIdx.x >> 9;    // 4 N-blocks
    const int mbase = bm * 64;
    const int nbase = bn * 128;

    // A-tile load mapping: 64 rows x 16 k, one float4 per thread
    const int aRow = tid >> 2;
    const int aK   = (tid & 3) * 4;
    const int m    = mbase + aRow;
    const int t    = m >> 5;           // m / B
    const int b    = m & 31;           // m % B
    const size_t srcRow = (size_t)(src_tmajor ? m : (b * TT + t)) * KK;
    const float* __restrict__ nrow = noise + (size_t)b * KK;

    // B-tile load mapping: 128 n-rows x 16 k, two float4 per thread
    const int wRow = tid >> 1;
    const int wK   = (tid & 1) * 8;
    const size_t wBase = (size_t)(nbase + wRow) * KK;

    // compute mapping: 4 m-rows, 4+4 n-cols (second half at +64)
    const int tm = (tid >> 4) * 4;
    const int tn = (tid & 15) * 4;

    float acc[4][8];
#pragma unroll
    for (int i = 0; i < 4; ++i)
#pragma unroll
        for (int j = 0; j < 8; ++j) acc[i][j] = 0.f;

    for (int k0 = 0; k0 < KK; k0 += 16) {
        __syncthreads();
        {   // A tile (noise folded in at load)
            float4 v  = *(const float4*)(src + srcRow + k0 + aK);
            float4 nz = *(const float4*)(nrow + k0 + aK);
            As[aK + 0][aRow] = v.x * nz.x;
            As[aK + 1][aRow] = v.y * nz.y;
            As[aK + 2][aRow] = v.z * nz.z;
            As[aK + 3][aRow] = v.w * nz.w;
        }
        {   // B tile (transposed into [k][n])
            float4 v0 = *(const float4*)(wih + wBase + k0 + wK);
            float4 v1 = *(const float4*)(wih + wBase + k0 + wK + 4);
            Bs[wK + 0][wRow] = v0.x;
            Bs[wK + 1][wRow] = v0.y;
            Bs[wK + 2][wRow] = v0.z;
            Bs[wK + 3][wRow] = v0.w;
            Bs[wK + 4][wRow] = v1.x;
            Bs[wK + 5][wRow] = v1.y;
            Bs[wK + 6][wRow] = v1.z;
            Bs[wK + 7][wRow] = v1.w;
        }
        __syncthreads();
#pragma unroll
        for (int kk = 0; kk < 16; ++kk) {
            float4 a  = *(const float4*)&As[kk][tm];
            float4 bL = *(const float4*)&Bs[kk][tn];
            float4 bH = *(const float4*)&Bs[kk][tn + 64];
            float av[4] = {a.x, a.y, a.z, a.w};
            float bv[8] = {bL.x, bL.y, bL.z, bL.w, bH.x, bH.y, bH.z, bH.w};
#pragma unroll
            for (int i = 0; i < 4; ++i)
#pragma unroll
                for (int j = 0; j < 8; ++j)
                    acc[i][j] = fmaf(av[i], bv[j], acc[i][j]);
        }
    }

    float4 bL = *(const float4*)(bih + nbase + tn);
    float4 bH = *(const float4*)(bih + nbase + tn + 64);
#pragma unroll
    for (int i = 0; i < 4; ++i) {
        size_t row = (size_t)(mbase + tm + i) * HH;
        float4 o0 = {acc[i][0] + bL.x, acc[i][1] + bL.y,
                     acc[i][2] + bL.z, acc[i][3] + bL.w};
        float4 o1 = {acc[i][4] + bH.x, acc[i][5] + bH.y,
                     acc[i][6] + bH.z, acc[i][7] + bH.w};
        *(float4*)(dst + row + nbase + tn)      = o0;
        *(float4*)(dst + row + nbase + tn + 64) = o1;
    }
}

// ---------------------------------------------------------------------------
// Recurrence for one layer. One workgroup per (direction, batch) stream:
// 64 blocks x 512 threads, thread n owns output column n. No inter-WG sync —
// streams are fully independent. h kept in registers; only g = h*noise_h is
// exchanged via LDS (2 __syncthreads per step).
// Per step: acc[n] = sum_k g[k] * W_hh[n,k]  (thread-n reads row n, streaming
// float4; rows live in L1/L2 — W_hh (1MB/cell) is L2-resident).
// ---------------------------------------------------------------------------
__global__ __launch_bounds__(512)
void rec_kernel(const float* __restrict__ xinF, const float* __restrict__ xinB,
                const float* __restrict__ whh, const float* __restrict__ bhh,
                const float* __restrict__ noiseh, const float* __restrict__ mask,
                float* __restrict__ outBase, float* __restrict__ finals,
                int layer, int out_tmajor)
{
    __shared__ __align__(16) float gbuf[HH];

    const int w = blockIdx.x;
    const int d = w >> 5;      // 0 = forward, 1 = backward
    const int b = w & 31;
    const int c = layer * 2 + d;

    const float* __restrict__ xin = d ? xinB : xinF;
    const float* __restrict__ W   = whh + (size_t)c * HH * HH;
    const int n = threadIdx.x;

    const float nhv = noiseh[(size_t)(c * BB + b) * HH + n];
    const float bhv = bhh[(size_t)c * HH + n];
    const float4* __restrict__ wrow = (const float4*)(W + (size_t)n * HH);

    float h = 0.f;

    for (int s = 0; s < TT; ++s) {
        const int t = d ? (TT - 1 - s) : s;

        gbuf[n] = h * nhv;
        __syncthreads();

        float4 accv = {0.f, 0.f, 0.f, 0.f};
        const float4* __restrict__ g4 = (const float4*)gbuf;
#pragma unroll 8
        for (int k = 0; k < HH / 4; ++k) {
            float4 g  = g4[k];
            float4 wv = wrow[k];
            accv.x = fmaf(g.x, wv.x, accv.x);
            accv.y = fmaf(g.y, wv.y, accv.y);
            accv.z = fmaf(g.z, wv.z, accv.z);
            accv.w = fmaf(g.w, wv.w, accv.w);
        }
        float acc = (accv.x + accv.y) + (accv.z + accv.w);

        const float mval = mask[(size_t)b * TT + t];
        const float xv   = xin[((size_t)t * BB + b) * HH + n];
        float hnew = tanhf(acc + xv + bhv);
        h = h + mval * (hnew - h);      // mask gating: h = hnew*m + h*(1-m)

        __syncthreads();   // all reads of gbuf done before next step overwrites

        const size_t o = out_tmajor ? ((size_t)(t * BB + b) * 1024)
                                    : ((size_t)(b * TT + t) * 1024);
        outBase[o + d * HH + n] = h;
    }

    finals[(size_t)(c * BB + b) * HH + n] = h;
}

// ---------------------------------------------------------------------------
extern "C" void kernel_launch(void* const* d_in, const int* in_sizes, int n_in,
                              void* d_out, int out_size, void* d_ws, size_t ws_size,
                              hipStream_t stream)
{
    (void)in_sizes; (void)n_in; (void)out_size; (void)ws_size;

    const float* x    = (const float*)d_in[0];   // [B,T,1024]
    const float* mask = (const float*)d_in[1];   // [B,T]
    const float* wih  = (const float*)d_in[2];   // [4,512,1024]
    const float* whh  = (const float*)d_in[3];   // [4,512,512]
    const float* bih  = (const float*)d_in[4];   // [4,512]
    const float* bhh  = (const float*)d_in[5];   // [4,512]
    const float* nin  = (const float*)d_in[6];   // [4,B,1024]
    const float* nh   = (const float*)d_in[7];   // [4,B,512]

    float* out    = (float*)d_out;
    float* xinF   = (float*)d_ws;                       // [T,B,512]  67.1 MB
    float* xinB   = xinF + (size_t)TT * BB * HH;        // [T,B,512]  67.1 MB
    float* seq0   = out;                                // [T,B,1024] staged in d_out
    float* finals = out + (size_t)BB * TT * 1024;       // [4,B,512]

    // ---- layer 0: projections from x ([B,T,K] -> tmajor=0)
    proj_kernel<<<2048, 256, 0, stream>>>(x, nin + 0 * (size_t)BB * KK,
                                          wih + 0 * (size_t)HH * KK,
                                          bih + 0 * HH, xinF, 0);
    proj_kernel<<<2048, 256, 0, stream>>>(x, nin + 1 * (size_t)BB * KK,
                                          wih + 1 * (size_t)HH * KK,
                                          bih + 1 * HH, xinB, 0);
    // ---- layer 0: recurrence -> seq0 [T,B,2H] (t-major), finals c=0,1
    rec_kernel<<<64, 512, 0, stream>>>(xinF, xinB, whh, bhh, nh, mask,
                                       seq0, finals, 0, 1);
    // ---- layer 1: projections from seq0 ([T,B,K] -> tmajor=1)
    proj_kernel<<<2048, 256, 0, stream>>>(seq0, nin + 2 * (size_t)BB * KK,
                                          wih + 2 * (size_t)HH * KK,
                                          bih + 2 * HH, xinF, 1);
    proj_kernel<<<2048, 256, 0, stream>>>(seq0, nin + 3 * (size_t)BB * KK,
                                          wih + 3 * (size_t)HH * KK,
                                          bih + 3 * HH, xinB, 1);
    // ---- layer 1: recurrence -> out [B,T,2H] (b-major), finals c=2,3
    rec_kernel<<<64, 512, 0, stream>>>(xinF, xinB, whh, bhh, nh, mask,
                                       out, finals, 1, 0);
}

// Round 2
// 24518.877 us; speedup vs baseline: 2.4470x; 2.4470x over previous
//
#include <hip/hip_runtime.h>
#include <math.h>

// VarMaskedRNN: B=32, T=1024, IN=1024, H=512, L=2, D=2, fp32 in/out.
// proj: fp32 tiled GEMM (unchanged from R1, ~450us each, works).
// rec:  REWRITTEN. Per direction: 32 blocks, each owns a 16-row slice of
//       W_hh resident in LDS (fp16) for the whole time loop. Per step each
//       block computes its slice for ALL 32 batches (32x16x512 mini-GEMM,
//       k-split 16 with rotated k-phase for conflict-free LDS), blocks
//       exchange g = h*noise_h (fp16) via double-buffered global buffer +
//       per-direction atomic counter barrier (agent scope, cross-XCD safe).
//       64 blocks <= 256 CUs -> co-resident, spin cannot deadlock.

#define BB 32
#define TT 1024
#define HH 512
#define KK 1024

typedef _Float16 half2_t __attribute__((ext_vector_type(2)));

// ---------------------------------------------------------------------------
// proj (unchanged from round 1)
// ---------------------------------------------------------------------------
__global__ __launch_bounds__(256)
void proj_kernel(const float* __restrict__ src, const float* __restrict__ noise,
                 const float* __restrict__ wih, const float* __restrict__ bih,
                 float* __restrict__ dst, int src_tmajor)
{
    __shared__ float As[16][68];
    __shared__ float Bs[16][132];

    const int tid = threadIdx.x;
    const int bm = blockIdx.x & 511;
    const int bn = blockIdx.x >> 9;
    const int mbase = bm * 64;
    const int nbase = bn * 128;

    const int aRow = tid >> 2;
    const int aK   = (tid & 3) * 4;
    const int m    = mbase + aRow;
    const int t    = m >> 5;
    const int b    = m & 31;
    const size_t srcRow = (size_t)(src_tmajor ? m : (b * TT + t)) * KK;
    const float* __restrict__ nrow = noise + (size_t)b * KK;

    const int wRow = tid >> 1;
    const int wK   = (tid & 1) * 8;
    const size_t wBase = (size_t)(nbase + wRow) * KK;

    const int tm = (tid >> 4) * 4;
    const int tn = (tid & 15) * 4;

    float acc[4][8];
#pragma unroll
    for (int i = 0; i < 4; ++i)
#pragma unroll
        for (int j = 0; j < 8; ++j) acc[i][j] = 0.f;

    for (int k0 = 0; k0 < KK; k0 += 16) {
        __syncthreads();
        {
            float4 v  = *(const float4*)(src + srcRow + k0 + aK);
            float4 nz = *(const float4*)(nrow + k0 + aK);
            As[aK + 0][aRow] = v.x * nz.x;
            As[aK + 1][aRow] = v.y * nz.y;
            As[aK + 2][aRow] = v.z * nz.z;
            As[aK + 3][aRow] = v.w * nz.w;
        }
        {
            float4 v0 = *(const float4*)(wih + wBase + k0 + wK);
            float4 v1 = *(const float4*)(wih + wBase + k0 + wK + 4);
            Bs[wK + 0][wRow] = v0.x;
            Bs[wK + 1][wRow] = v0.y;
            Bs[wK + 2][wRow] = v0.z;
            Bs[wK + 3][wRow] = v0.w;
            Bs[wK + 4][wRow] = v1.x;
            Bs[wK + 5][wRow] = v1.y;
            Bs[wK + 6][wRow] = v1.z;
            Bs[wK + 7][wRow] = v1.w;
        }
        __syncthreads();
#pragma unroll
        for (int kk = 0; kk < 16; ++kk) {
            float4 a  = *(const float4*)&As[kk][tm];
            float4 bL = *(const float4*)&Bs[kk][tn];
            float4 bH = *(const float4*)&Bs[kk][tn + 64];
            float av[4] = {a.x, a.y, a.z, a.w};
            float bv[8] = {bL.x, bL.y, bL.z, bL.w, bH.x, bH.y, bH.z, bH.w};
#pragma unroll
            for (int i = 0; i < 4; ++i)
#pragma unroll
                for (int j = 0; j < 8; ++j)
                    acc[i][j] = fmaf(av[i], bv[j], acc[i][j]);
        }
    }

    float4 bL = *(const float4*)(bih + nbase + tn);
    float4 bH = *(const float4*)(bih + nbase + tn + 64);
#pragma unroll
    for (int i = 0; i < 4; ++i) {
        size_t row = (size_t)(mbase + tm + i) * HH;
        float4 o0 = {acc[i][0] + bL.x, acc[i][1] + bL.y,
                     acc[i][2] + bL.z, acc[i][3] + bL.w};
        float4 o1 = {acc[i][4] + bH.x, acc[i][5] + bH.y,
                     acc[i][6] + bH.z, acc[i][7] + bH.w};
        *(float4*)(dst + row + nbase + tn)      = o0;
        *(float4*)(dst + row + nbase + tn + 64) = o1;
    }
}

// ---------------------------------------------------------------------------
// rec2: pipelined recurrence.
// grid = 64 blocks x 256 threads. block -> (d = bx&1, slice = bx>>1).
// Each block owns rows [slice*16, slice*16+16) of W_hh (LDS, fp16).
// g-exchange buffer (global, fp16): per (layer,dir,slot): [256 k2][32 b] half2.
// ---------------------------------------------------------------------------
#define GS_STRIDE 36   // half2 units per k2 row (32 + 4 pad)
#define WS_STRIDE 20   // half2 units per k2 row (16 + 4 pad)
#define AUX_STRIDE 18

__global__ __launch_bounds__(256)
void rec2_kernel(const float* __restrict__ xinF, const float* __restrict__ xinB,
                 const float* __restrict__ whh, const float* __restrict__ bhh,
                 const float* __restrict__ nh, const float* __restrict__ maskp,
                 float* __restrict__ outBase, float* __restrict__ finals,
                 half2_t* __restrict__ gbase, unsigned* __restrict__ cbase,
                 int layer, int out_tmajor)
{
    __shared__ half2_t gs2[256 * GS_STRIDE];   // 36864 B
    __shared__ half2_t ws2[256 * WS_STRIDE];   // 20480 B
    __shared__ float outs[32 * AUX_STRIDE];    // 2304 B
    __shared__ float hold[32 * AUX_STRIDE];
    __shared__ float xin_s[32 * AUX_STRIDE];
    __shared__ float mask_s[32];

    const int tid   = threadIdx.x;
    const int d     = blockIdx.x & 1;
    const int slice = blockIdx.x >> 1;
    const int c     = layer * 2 + d;

    const float* __restrict__ xin = d ? xinB : xinF;
    unsigned* cnt = cbase + (size_t)(layer * 2 + d) * 64;
    half2_t* gsl0 = gbase + (size_t)((layer * 2 + d) * 2 + 0) * 8192;
    half2_t* gsl1 = gbase + (size_t)((layer * 2 + d) * 2 + 1) * 8192;

    // ---- main-loop thread mapping
    const int sk   = tid & 15;          // k-split id
    const int tile = tid >> 4;          // 0..15
    const int tb0  = (tile & 7) * 4;    // batch base
    const int tn0  = (tile >> 3) * 8;   // n base within slice

    // ---- pass-A mapping (epilogue: tanh/mask/g-write)
    const int pb = tid & 31;            // batch
    const int pnp = tid >> 5;           // n-pair 0..7
    const int pn = pnp * 2;
    const float bh0 = bhh[(size_t)c * HH + slice * 16 + pn];
    const float bh1 = bhh[(size_t)c * HH + slice * 16 + pn + 1];
    const float nh0 = nh[((size_t)c * BB + pb) * HH + slice * 16 + pn];
    const float nh1 = nh[((size_t)c * BB + pb) * HH + slice * 16 + pn + 1];

    // ---- pass-B mapping (coalesced out-write / xin-stage)
    const int qb = tid >> 3;
    const int qn = (tid & 7) * 2;

    // ---- prologue: W slice -> LDS (fp16), zero h, stage xin/mask for t0
    {
        const int n  = tid >> 4;             // 0..15
        const int kc = (tid & 15) * 32;      // fp32-k base
        const float* wr = whh + ((size_t)c * HH + slice * 16 + n) * HH + kc;
#pragma unroll
        for (int j = 0; j < 16; ++j) {
            half2_t hv = {(_Float16)wr[2 * j], (_Float16)wr[2 * j + 1]};
            ws2[(kc / 2 + j) * WS_STRIDE + n] = hv;
        }
    }
    for (int idx = tid; idx < 32 * AUX_STRIDE; idx += 256) hold[idx] = 0.f;
    {
        const int t0 = d ? (TT - 1) : 0;
        float2 v = *(const float2*)(xin + ((size_t)t0 * BB + qb) * HH + slice * 16 + qn);
        *(float2*)&xin_s[qb * AUX_STRIDE + qn] = v;
        if (tid < 32) mask_s[tid] = maskp[(size_t)tid * TT + t0];
    }
    __syncthreads();

    for (int s = 0; s < TT; ++s) {
        const int t = d ? (TT - 1 - s) : s;

        // B1: wait for step s-1 g-writes from all 32 same-direction blocks
        if (tid == 0 && s > 0) {
            const unsigned target = 32u * (unsigned)s;
            unsigned it = 0;
            while (__hip_atomic_load(cnt, __ATOMIC_ACQUIRE,
                                     __HIP_MEMORY_SCOPE_AGENT) < target) {
                __builtin_amdgcn_s_sleep(2);
                if (++it > (1u << 26)) break;   // fail visibly, never hang
            }
        }
        __syncthreads();

        // stage g (fp16, 32 KB): thread tid loads k2-row tid (128 B)
        {
            const half2_t* gr = (s & 1) ? gsl1 : gsl0;
            const uint4* gp = (const uint4*)(gr + (size_t)tid * 32);
            uint4* dst = (uint4*)&gs2[tid * GS_STRIDE];
#pragma unroll
            for (int j = 0; j < 8; ++j) dst[j] = gp[j];
        }
        __syncthreads();   // B2: gs2 + xin_s ready

        // main: acc[4b][8n] over this thread's 32-k chunk (16 half2, rotated)
        float acc[4][8];
#pragma unroll
        for (int i = 0; i < 4; ++i)
#pragma unroll
            for (int j = 0; j < 8; ++j) acc[i][j] = 0.f;

        const int kbase = sk * 16;
#pragma unroll
        for (int i = 0; i < 16; ++i) {
            const int k2 = kbase + ((i + sk) & 15);
            const half2_t* gp = &gs2[k2 * GS_STRIDE + tb0];
            const half2_t* wp = &ws2[k2 * WS_STRIDE + tn0];
            half2_t gv[4], wv[8];
#pragma unroll
            for (int x = 0; x < 4; ++x) gv[x] = gp[x];
#pragma unroll
            for (int x = 0; x < 8; ++x) wv[x] = wp[x];
#pragma unroll
            for (int bi = 0; bi < 4; ++bi)
#pragma unroll
                for (int nj = 0; nj < 8; ++nj) {
#if __has_builtin(__builtin_amdgcn_fdot2)
                    acc[bi][nj] = __builtin_amdgcn_fdot2(gv[bi], wv[nj],
                                                         acc[bi][nj], false);
#else
                    acc[bi][nj] = fmaf((float)gv[bi].x, (float)wv[nj].x,
                                       acc[bi][nj]);
                    acc[bi][nj] = fmaf((float)gv[bi].y, (float)wv[nj].y,
                                       acc[bi][nj]);
#endif
                }
        }

        // reduce across 16 k-split lanes (consecutive lanes, xor butterfly)
#pragma unroll
        for (int bi = 0; bi < 4; ++bi)
#pragma unroll
            for (int nj = 0; nj < 8; ++nj) {
                float v = acc[bi][nj];
                v += __shfl_xor(v, 1);
                v += __shfl_xor(v, 2);
                v += __shfl_xor(v, 4);
                v += __shfl_xor(v, 8);
                if (sk == 0) outs[(tb0 + bi) * AUX_STRIDE + (tn0 + nj)] = v;
            }
        __syncthreads();   // B3: outs = raw recurrent sums

        // pass A: h_new = tanh(sum + xin + bh); mask-blend; write g (fp16)
        {
            const int o0 = pb * AUX_STRIDE + pn;
            float pre0 = outs[o0]     + xin_s[o0]     + bh0;
            float pre1 = outs[o0 + 1] + xin_s[o0 + 1] + bh1;
            float m  = mask_s[pb];
            float h0 = hold[o0], h1 = hold[o0 + 1];
            float v0 = tanhf(pre0), v1 = tanhf(pre1);
            float hn0 = h0 + m * (v0 - h0);
            float hn1 = h1 + m * (v1 - h1);
            hold[o0] = hn0;  hold[o0 + 1] = hn1;
            outs[o0] = hn0;  outs[o0 + 1] = hn1;
            half2_t gvo = {(_Float16)(hn0 * nh0), (_Float16)(hn1 * nh1)};
            half2_t* gw = ((s + 1) & 1) ? gsl1 : gsl0;
            gw[(size_t)(slice * 8 + pnp) * 32 + pb] = gvo;
        }
        __syncthreads();   // B4: g-stores drained (vmcnt0 before barrier)

        if (tid == 0)
            __hip_atomic_fetch_add(cnt, 1u, __ATOMIC_RELEASE,
                                   __HIP_MEMORY_SCOPE_AGENT);

        // pass B: coalesced out-write (overlaps other blocks' spin)
        {
            float2 v = *(const float2*)&outs[qb * AUX_STRIDE + qn];
            const size_t o = out_tmajor
                ? ((size_t)(t * BB + qb) * 1024)
                : ((size_t)(qb * TT + t) * 1024);
            *(float2*)(outBase + o + d * HH + slice * 16 + qn) = v;
        }

        // stage xin/mask for next step (read by NEXT pass A, after next B2)
        if (s + 1 < TT) {
            const int tn = d ? (TT - 2 - s) : (s + 1);
            float2 v = *(const float2*)(xin + ((size_t)tn * BB + qb) * HH
                                        + slice * 16 + qn);
            *(float2*)&xin_s[qb * AUX_STRIDE + qn] = v;
            if (tid < 32) mask_s[tid] = maskp[(size_t)tid * TT + tn];
        }
    }

    // finals from hold (coalesced)
    {
        float2 v = *(const float2*)&hold[qb * AUX_STRIDE + qn];
        *(float2*)(finals + ((size_t)c * BB + qb) * HH + slice * 16 + qn) = v;
    }
}

// ---------------------------------------------------------------------------
extern "C" void kernel_launch(void* const* d_in, const int* in_sizes, int n_in,
                              void* d_out, int out_size, void* d_ws, size_t ws_size,
                              hipStream_t stream)
{
    (void)in_sizes; (void)n_in; (void)out_size; (void)ws_size;

    const float* x    = (const float*)d_in[0];
    const float* mask = (const float*)d_in[1];
    const float* wih  = (const float*)d_in[2];
    const float* whh  = (const float*)d_in[3];
    const float* bih  = (const float*)d_in[4];
    const float* bhh  = (const float*)d_in[5];
    const float* nin  = (const float*)d_in[6];
    const float* nh   = (const float*)d_in[7];

    float* out    = (float*)d_out;
    float* xinF   = (float*)d_ws;                       // [T,B,512]
    float* xinB   = xinF + (size_t)TT * BB * HH;        // [T,B,512]
    half2_t* gbase = (half2_t*)(xinB + (size_t)TT * BB * HH);  // 256 KB
    unsigned* cnt  = (unsigned*)((char*)gbase + 8 * 8192 * 4); // 2 KB
    float* seq0   = out;                                // [T,B,1024] staging
    float* finals = out + (size_t)BB * TT * 1024;

    // zero g-exchange buffers + sync counters (ws is poisoned each launch)
    hipMemsetAsync(gbase, 0, 8 * 8192 * 4 + 2048, stream);

    // ---- layer 0
    proj_kernel<<<2048, 256, 0, stream>>>(x, nin + 0 * (size_t)BB * KK,
                                          wih + 0 * (size_t)HH * KK,
                                          bih + 0 * HH, xinF, 0);
    proj_kernel<<<2048, 256, 0, stream>>>(x, nin + 1 * (size_t)BB * KK,
                                          wih + 1 * (size_t)HH * KK,
                                          bih + 1 * HH, xinB, 0);
    rec2_kernel<<<64, 256, 0, stream>>>(xinF, xinB, whh, bhh, nh, mask,
                                        seq0, finals, gbase, cnt, 0, 1);
    // ---- layer 1
    proj_kernel<<<2048, 256, 0, stream>>>(seq0, nin + 2 * (size_t)BB * KK,
                                          wih + 2 * (size_t)HH * KK,
                                          bih + 2 * HH, xinF, 1);
    proj_kernel<<<2048, 256, 0, stream>>>(seq0, nin + 3 * (size_t)BB * KK,
                                          wih + 3 * (size_t)HH * KK,
                                          bih + 3 * HH, xinB, 1);
    rec2_kernel<<<64, 256, 0, stream>>>(xinF, xinB, whh, bhh, nh, mask,
                                        out, finals, gbase, cnt, 1, 0);
}

// Round 4
// 22889.917 us; speedup vs baseline: 2.6211x; 1.0712x over previous
//
#include <hip/hip_runtime.h>
#include <math.h>

// VarMaskedRNN: B=32, T=1024, IN=1024, H=512, L=2, D=2, fp32 in/out.
// proj: fp32 tiled GEMM (unchanged, ~450us each).
// rec:  32 blocks/direction each own a 16-row W_hh slice in LDS (fp16).
//       Cross-block g-exchange via RELAXED agent-scope atomics (sc1 bypass,
//       hit the coherent point directly -> NO buffer_inv / buffer_wbl2 flash
//       ops, local L2 stays warm). Per-block flags on private cachelines
//       (no shared-line RMW ping-pong). Ordering: g sc1-stores ->
//       __syncthreads (vmcnt(0) drain) -> flag sc1-store; readers poll flags
//       (lane-parallel relaxed) then sc1-load g. 64 blocks co-resident.
//
// [resubmission of round-3 kernel: previous bench died on GPU acquisition]

#define BB 32
#define TT 1024
#define HH 512
#define KK 1024

typedef _Float16 half2_t __attribute__((ext_vector_type(2)));

// ---------------------------------------------------------------------------
// proj (unchanged from round 1)
// ---------------------------------------------------------------------------
__global__ __launch_bounds__(256)
void proj_kernel(const float* __restrict__ src, const float* __restrict__ noise,
                 const float* __restrict__ wih, const float* __restrict__ bih,
                 float* __restrict__ dst, int src_tmajor)
{
    __shared__ float As[16][68];
    __shared__ float Bs[16][132];

    const int tid = threadIdx.x;
    const int bm = blockIdx.x & 511;
    const int bn = blockIdx.x >> 9;
    const int mbase = bm * 64;
    const int nbase = bn * 128;

    const int aRow = tid >> 2;
    const int aK   = (tid & 3) * 4;
    const int m    = mbase + aRow;
    const int t    = m >> 5;
    const int b    = m & 31;
    const size_t srcRow = (size_t)(src_tmajor ? m : (b * TT + t)) * KK;
    const float* __restrict__ nrow = noise + (size_t)b * KK;

    const int wRow = tid >> 1;
    const int wK   = (tid & 1) * 8;
    const size_t wBase = (size_t)(nbase + wRow) * KK;

    const int tm = (tid >> 4) * 4;
    const int tn = (tid & 15) * 4;

    float acc[4][8];
#pragma unroll
    for (int i = 0; i < 4; ++i)
#pragma unroll
        for (int j = 0; j < 8; ++j) acc[i][j] = 0.f;

    for (int k0 = 0; k0 < KK; k0 += 16) {
        __syncthreads();
        {
            float4 v  = *(const float4*)(src + srcRow + k0 + aK);
            float4 nz = *(const float4*)(nrow + k0 + aK);
            As[aK + 0][aRow] = v.x * nz.x;
            As[aK + 1][aRow] = v.y * nz.y;
            As[aK + 2][aRow] = v.z * nz.z;
            As[aK + 3][aRow] = v.w * nz.w;
        }
        {
            float4 v0 = *(const float4*)(wih + wBase + k0 + wK);
            float4 v1 = *(const float4*)(wih + wBase + k0 + wK + 4);
            Bs[wK + 0][wRow] = v0.x;
            Bs[wK + 1][wRow] = v0.y;
            Bs[wK + 2][wRow] = v0.z;
            Bs[wK + 3][wRow] = v0.w;
            Bs[wK + 4][wRow] = v1.x;
            Bs[wK + 5][wRow] = v1.y;
            Bs[wK + 6][wRow] = v1.z;
            Bs[wK + 7][wRow] = v1.w;
        }
        __syncthreads();
#pragma unroll
        for (int kk = 0; kk < 16; ++kk) {
            float4 a  = *(const float4*)&As[kk][tm];
            float4 bL = *(const float4*)&Bs[kk][tn];
            float4 bH = *(const float4*)&Bs[kk][tn + 64];
            float av[4] = {a.x, a.y, a.z, a.w};
            float bv[8] = {bL.x, bL.y, bL.z, bL.w, bH.x, bH.y, bH.z, bH.w};
#pragma unroll
            for (int i = 0; i < 4; ++i)
#pragma unroll
                for (int j = 0; j < 8; ++j)
                    acc[i][j] = fmaf(av[i], bv[j], acc[i][j]);
        }
    }

    float4 bL = *(const float4*)(bih + nbase + tn);
    float4 bH = *(const float4*)(bih + nbase + tn + 64);
#pragma unroll
    for (int i = 0; i < 4; ++i) {
        size_t row = (size_t)(mbase + tm + i) * HH;
        float4 o0 = {acc[i][0] + bL.x, acc[i][1] + bL.y,
                     acc[i][2] + bL.z, acc[i][3] + bL.w};
        float4 o1 = {acc[i][4] + bH.x, acc[i][5] + bH.y,
                     acc[i][6] + bH.z, acc[i][7] + bH.w};
        *(float4*)(dst + row + nbase + tn)      = o0;
        *(float4*)(dst + row + nbase + tn + 64) = o1;
    }
}

// ---------------------------------------------------------------------------
// rec3: fence-free sc1 exchange + per-block flag barrier.
// grid = 64 blocks x 256 threads. block -> (d = bx&1, slice = bx>>1).
// g buffers (global): per (layer,dir,slot): [256 k2][32 b] half2 = 32 KB.
// flags (global): per (layer,dir): 32 flags, 64 B apart.
// ---------------------------------------------------------------------------
#define GS_STRIDE 36   // half2 per k2 row (32 + 4 pad)
#define WS_STRIDE 20   // half2 per k2 row (16 + 4 pad)
#define AUX_STRIDE 18

union h2u { half2_t h; unsigned u; };

__global__ __launch_bounds__(256)
void rec3_kernel(const float* __restrict__ xinF, const float* __restrict__ xinB,
                 const float* __restrict__ whh, const float* __restrict__ bhh,
                 const float* __restrict__ nh, const float* __restrict__ maskp,
                 float* __restrict__ outBase, float* __restrict__ finals,
                 unsigned* __restrict__ gbase, unsigned* __restrict__ fbase,
                 int layer, int out_tmajor)
{
    __shared__ __align__(16) half2_t gs2[256 * GS_STRIDE];
    __shared__ __align__(16) half2_t ws2[256 * WS_STRIDE];
    __shared__ float outs[32 * AUX_STRIDE];
    __shared__ float hold[32 * AUX_STRIDE];
    __shared__ float xin_s[32 * AUX_STRIDE];
    __shared__ float mask_s[32];

    const int tid   = threadIdx.x;
    const int d     = blockIdx.x & 1;
    const int slice = blockIdx.x >> 1;
    const int c     = layer * 2 + d;

    const float* __restrict__ xin = d ? xinB : xinF;
    unsigned* flags = fbase + (size_t)(layer * 2 + d) * 512;  // 32 x 16 uints
    unsigned* gsl0  = gbase + (size_t)((layer * 2 + d) * 2 + 0) * 8192;
    unsigned* gsl1  = gbase + (size_t)((layer * 2 + d) * 2 + 1) * 8192;

    // main-loop mapping
    const int sk   = tid & 15;
    const int tile = tid >> 4;
    const int tb0  = (tile & 7) * 4;
    const int tn0  = (tile >> 3) * 8;

    // pass-A mapping
    const int pb  = tid & 31;
    const int pnp = tid >> 5;
    const int pn  = pnp * 2;
    const float bh0 = bhh[(size_t)c * HH + slice * 16 + pn];
    const float bh1 = bhh[(size_t)c * HH + slice * 16 + pn + 1];
    const float nh0 = nh[((size_t)c * BB + pb) * HH + slice * 16 + pn];
    const float nh1 = nh[((size_t)c * BB + pb) * HH + slice * 16 + pn + 1];

    // pass-B mapping
    const int qb = tid >> 3;
    const int qn = (tid & 7) * 2;

    // prologue: W slice -> LDS fp16; zero h; stage xin/mask for t0
    {
        const int n  = tid >> 4;
        const int kc = (tid & 15) * 32;
        const float* wr = whh + ((size_t)c * HH + slice * 16 + n) * HH + kc;
#pragma unroll
        for (int j = 0; j < 16; ++j) {
            half2_t hv = {(_Float16)wr[2 * j], (_Float16)wr[2 * j + 1]};
            ws2[(kc / 2 + j) * WS_STRIDE + n] = hv;
        }
    }
    for (int idx = tid; idx < 32 * AUX_STRIDE; idx += 256) hold[idx] = 0.f;
    {
        const int t0 = d ? (TT - 1) : 0;
        float2 v = *(const float2*)(xin + ((size_t)t0 * BB + qb) * HH + slice * 16 + qn);
        *(float2*)&xin_s[qb * AUX_STRIDE + qn] = v;
        if (tid < 32) mask_s[tid] = maskp[(size_t)tid * TT + t0];
    }
    __syncthreads();

    for (int s = 0; s < TT; ++s) {
        const int t = d ? (TT - 1 - s) : s;

        // B1: wait until all 32 blocks posted flag >= s (relaxed, lane-parallel,
        // private cachelines -> no L2 flash ops, no RMW contention)
        if (s > 0) {
            if (tid < 64) {
                const unsigned target = (unsigned)s;
                unsigned* fp = &flags[(tid & 31) * 16];
                unsigned it = 0;
                for (;;) {
                    unsigned v = __hip_atomic_load(fp, __ATOMIC_RELAXED,
                                                   __HIP_MEMORY_SCOPE_AGENT);
                    if (__all(v >= target)) break;
                    __builtin_amdgcn_s_sleep(1);
                    if (++it > (1u << 24)) break;   // fail visibly, never hang
                }
            }
            __syncthreads();
        }

        // stage g: thread tid sc1-loads k2-row tid (128 B) -> LDS
        {
            const unsigned* gr = (s & 1) ? gsl1 : gsl0;
            const unsigned long long* gp =
                (const unsigned long long*)(gr + (size_t)tid * 32);
            unsigned long long* dst = (unsigned long long*)&gs2[tid * GS_STRIDE];
#pragma unroll
            for (int j = 0; j < 16; ++j)
                dst[j] = __hip_atomic_load(&gp[j], __ATOMIC_RELAXED,
                                           __HIP_MEMORY_SCOPE_AGENT);
        }
        __syncthreads();   // B2: gs2 + xin_s ready

        // main: acc[4b][8n] over this thread's 32-k chunk
        float acc[4][8];
#pragma unroll
        for (int i = 0; i < 4; ++i)
#pragma unroll
            for (int j = 0; j < 8; ++j) acc[i][j] = 0.f;

        const int kbase = sk * 16;
#pragma unroll
        for (int i = 0; i < 16; ++i) {
            const int k2 = kbase + ((i + sk) & 15);
            const half2_t* gp = &gs2[k2 * GS_STRIDE + tb0];
            const half2_t* wp = &ws2[k2 * WS_STRIDE + tn0];
            half2_t gv[4], wv[8];
#pragma unroll
            for (int x = 0; x < 4; ++x) gv[x] = gp[x];
#pragma unroll
            for (int x = 0; x < 8; ++x) wv[x] = wp[x];
#pragma unroll
            for (int bi = 0; bi < 4; ++bi)
#pragma unroll
                for (int nj = 0; nj < 8; ++nj) {
#if __has_builtin(__builtin_amdgcn_fdot2)
                    acc[bi][nj] = __builtin_amdgcn_fdot2(gv[bi], wv[nj],
                                                         acc[bi][nj], false);
#else
                    acc[bi][nj] = fmaf((float)gv[bi].x, (float)wv[nj].x,
                                       acc[bi][nj]);
                    acc[bi][nj] = fmaf((float)gv[bi].y, (float)wv[nj].y,
                                       acc[bi][nj]);
#endif
                }
        }

        // k-split reduce (16 consecutive lanes)
#pragma unroll
        for (int bi = 0; bi < 4; ++bi)
#pragma unroll
            for (int nj = 0; nj < 8; ++nj) {
                float v = acc[bi][nj];
                v += __shfl_xor(v, 1);
                v += __shfl_xor(v, 2);
                v += __shfl_xor(v, 4);
                v += __shfl_xor(v, 8);
                if (sk == 0) outs[(tb0 + bi) * AUX_STRIDE + (tn0 + nj)] = v;
            }
        __syncthreads();   // B3

        // pass A: tanh + mask blend; sc1-store g for step s+1
        {
            const int o0 = pb * AUX_STRIDE + pn;
            float pre0 = outs[o0]     + xin_s[o0]     + bh0;
            float pre1 = outs[o0 + 1] + xin_s[o0 + 1] + bh1;
            float m  = mask_s[pb];
            float h0 = hold[o0], h1 = hold[o0 + 1];
            float v0 = tanhf(pre0), v1 = tanhf(pre1);
            float hn0 = h0 + m * (v0 - h0);
            float hn1 = h1 + m * (v1 - h1);
            hold[o0] = hn0;  hold[o0 + 1] = hn1;
            outs[o0] = hn0;  outs[o0 + 1] = hn1;
            if (s + 1 < TT) {
                h2u gvo;
                gvo.h = half2_t{(_Float16)(hn0 * nh0), (_Float16)(hn1 * nh1)};
                unsigned* gw = ((s + 1) & 1) ? gsl1 : gsl0;
                __hip_atomic_store(&gw[(size_t)(slice * 8 + pnp) * 32 + pb],
                                   gvo.u, __ATOMIC_RELAXED,
                                   __HIP_MEMORY_SCOPE_AGENT);
            }
        }
        __syncthreads();   // B4: vmcnt(0) before barrier => g stores ack'd

        // post flag = s+1 (own cacheline, relaxed sc1 store)
        if (tid == 0 && s + 1 < TT)
            __hip_atomic_store(&flags[slice * 16], (unsigned)(s + 1),
                               __ATOMIC_RELAXED, __HIP_MEMORY_SCOPE_AGENT);

        // pass B: coalesced out-write (overlaps other blocks' poll)
        {
            float2 v = *(const float2*)&outs[qb * AUX_STRIDE + qn];
            const size_t o = out_tmajor
                ? ((size_t)(t * BB + qb) * 1024)
                : ((size_t)(qb * TT + t) * 1024);
            *(float2*)(outBase + o + d * HH + slice * 16 + qn) = v;
        }

        // stage xin/mask for next step
        if (s + 1 < TT) {
            const int tn = d ? (TT - 2 - s) : (s + 1);
            float2 v = *(const float2*)(xin + ((size_t)tn * BB + qb) * HH
                                        + slice * 16 + qn);
            *(float2*)&xin_s[qb * AUX_STRIDE + qn] = v;
            if (tid < 32) mask_s[tid] = maskp[(size_t)tid * TT + tn];
        }
    }

    // finals
    {
        float2 v = *(const float2*)&hold[qb * AUX_STRIDE + qn];
        *(float2*)(finals + ((size_t)c * BB + qb) * HH + slice * 16 + qn) = v;
    }
}

// ---------------------------------------------------------------------------
extern "C" void kernel_launch(void* const* d_in, const int* in_sizes, int n_in,
                              void* d_out, int out_size, void* d_ws, size_t ws_size,
                              hipStream_t stream)
{
    (void)in_sizes; (void)n_in; (void)out_size; (void)ws_size;

    const float* x    = (const float*)d_in[0];
    const float* mask = (const float*)d_in[1];
    const float* wih  = (const float*)d_in[2];
    const float* whh  = (const float*)d_in[3];
    const float* bih  = (const float*)d_in[4];
    const float* bhh  = (const float*)d_in[5];
    const float* nin  = (const float*)d_in[6];
    const float* nh   = (const float*)d_in[7];

    float* out    = (float*)d_out;
    float* xinF   = (float*)d_ws;                        // [T,B,512]
    float* xinB   = xinF + (size_t)TT * BB * HH;         // [T,B,512]
    unsigned* gbase = (unsigned*)(xinB + (size_t)TT * BB * HH);  // 8 x 32 KB
    unsigned* fbase = gbase + 8 * 8192;                  // 4 x 2 KB flags
    float* seq0   = out;
    float* finals = out + (size_t)BB * TT * 1024;

    // zero g slot buffers + flags (ws is poisoned before every launch)
    hipMemsetAsync(gbase, 0, (8 * 8192 + 4 * 512) * sizeof(unsigned), stream);

    // ---- layer 0
    proj_kernel<<<2048, 256, 0, stream>>>(x, nin + 0 * (size_t)BB * KK,
                                          wih + 0 * (size_t)HH * KK,
                                          bih + 0 * HH, xinF, 0);
    proj_kernel<<<2048, 256, 0, stream>>>(x, nin + 1 * (size_t)BB * KK,
                                          wih + 1 * (size_t)HH * KK,
                                          bih + 1 * HH, xinB, 0);
    rec3_kernel<<<64, 256, 0, stream>>>(xinF, xinB, whh, bhh, nh, mask,
                                        seq0, finals, gbase, fbase, 0, 1);
    // ---- layer 1
    proj_kernel<<<2048, 256, 0, stream>>>(seq0, nin + 2 * (size_t)BB * KK,
                                          wih + 2 * (size_t)HH * KK,
                                          bih + 2 * HH, xinF, 1);
    proj_kernel<<<2048, 256, 0, stream>>>(seq0, nin + 3 * (size_t)BB * KK,
                                          wih + 3 * (size_t)HH * KK,
                                          bih + 3 * HH, xinB, 1);
    rec3_kernel<<<64, 256, 0, stream>>>(xinF, xinB, whh, bhh, nh, mask,
                                        out, finals, gbase, fbase, 1, 0);
}